// Round 3
// baseline (71.913 us; speedup 1.0000x reference)
//
#include <hip/hip_runtime.h>
#include <hip/hip_cooperative_groups.h>

namespace cg = cooperative_groups;

#define ORD 16
#define LCH 64
#define NB  256
#define CPB 64
#define PCH (NB*CPB)        // 16384 chunks; PCH*LCH = 2^20
#define QT  28              // truncated chunk-scan depth (0.6561^28 ~ 7e-6)

__global__ __launch_bounds__(256) void k_fused(const float* __restrict__ u,
                                               const float* __restrict__ A_w,
                                               const float* __restrict__ B_w,
                                               float* __restrict__ out,
                                               float* __restrict__ d_aos) {
    __shared__ float sR[16][ORD][ORD];   // M^r, r=0..15        16 KB
    __shared__ float sM[3][ORD][ORD];    // M^16, M^32, G=M^64   3 KB
    __shared__ float sG[QT][ORD][ORD];   // (G^m)^T             28 KB
    __shared__ float sV[ORD][LCH];       // V[j][k]=(a.M^k)[j]   4 KB
    __shared__ float sW[4][ORD];         // w_q = a.M^(16q)
    __shared__ float u_s[64][81];        // staged u            20.7 KB
    __shared__ float y_s[64][68];        // local y             17.4 KB
    __shared__ float sdl[64][ORD + 1];   // own end states       4.4 KB
    __shared__ float sd[CPB + QT - 1][ORD];  // neighbor d       5.8 KB
    __shared__ float sS[CPB][ORD];       // entry states         4 KB

    const int tid = threadIdx.x;
    const int b   = blockIdx.x;
    const int cb  = b * CPB;
    const long base = (long)cb * LCH;

    // ---- stage u[base .. base+4111] (coalesced float4 -> padded LDS) ----
    const float* ug = u + base;
    for (int g4 = tid; g4 < (CPB * LCH + ORD) / 4; g4 += 256) {
        const float4 v = ((const float4*)ug)[g4];
        const int g = g4 * 4;
        #pragma unroll
        for (int e = 0; e < 4; ++e) {
            const int idx = g + e, row = idx >> 6, col = idx & 63;
            const float f = (e == 0) ? v.x : (e == 1) ? v.y : (e == 2) ? v.z : v.w;
            if (row < 64) u_s[row][col] = f;
            if (col < ORD && row >= 1) u_s[row - 1][64 + col] = f;
        }
    }

    // ---- tables (every block, redundantly, in LDS) ----
    const int i = tid >> 4, j = tid & 15;
    sR[0][i][j] = (i == j) ? 1.f : 0.f;
    sR[1][i][j] = (i == 0) ? A_w[j] : ((j == i - 1) ? 1.f : 0.f);
    __syncthreads();
    int have = 1;
    while (have < 15) {                       // M^2..M^15 by doubling
        const int nn = (have < 15 - have) ? have : (15 - have);
        for (int idx = tid; idx < nn * 256; idx += 256) {
            const int m = (idx >> 8) + 1, ii = (idx >> 4) & 15, jj = idx & 15;
            float acc = 0.f;
            #pragma unroll
            for (int l = 0; l < ORD; ++l) acc += sR[have][ii][l] * sR[m][l][jj];
            sR[have + m][ii][jj] = acc;
        }
        __syncthreads(); have += nn;
    }
    { float acc = 0.f;
      #pragma unroll
      for (int l = 0; l < ORD; ++l) acc += sR[15][i][l] * sR[1][l][j];
      sM[0][i][j] = acc; }                    // M^16
    __syncthreads();
    { float acc = 0.f;
      #pragma unroll
      for (int l = 0; l < ORD; ++l) acc += sM[0][i][l] * sM[0][l][j];
      sM[1][i][j] = acc; }                    // M^32
    __syncthreads();
    { float acc = 0.f;
      #pragma unroll
      for (int l = 0; l < ORD; ++l) acc += sM[1][i][l] * sM[1][l][j];
      sM[2][i][j] = acc; }                    // G = M^64
    if (tid < ORD) sW[0][tid] = A_w[tid];
    __syncthreads();
    for (int q = 0; q < 3; ++q) {             // w_{q+1} = w_q . M^16
        if (tid < ORD) {
            float acc = 0.f;
            #pragma unroll
            for (int l = 0; l < ORD; ++l) acc += sW[q][l] * sM[0][l][tid];
            sW[q + 1][tid] = acc;
        }
        __syncthreads();
    }
    for (int idx = tid; idx < ORD * LCH; idx += 256) {  // V[j][k] = w_q . M^r
        const int k = idx >> 4, jj = idx & 15, q = k >> 4, r = k & 15;
        float acc = 0.f;
        #pragma unroll
        for (int l = 0; l < ORD; ++l) acc += sW[q][l] * sR[r][l][jj];
        sV[jj][k] = acc;
    }
    sG[0][i][j] = (i == j) ? 1.f : 0.f;
    sG[1][i][j] = sM[2][j][i];                // G^T
    __syncthreads();
    have = 1;
    while (have < QT - 1) {                   // (G^m)^T by doubling
        const int nn = (have < QT - 1 - have) ? have : (QT - 1 - have);
        for (int idx = tid; idx < nn * 256; idx += 256) {
            const int m = (idx >> 8) + 1, ii = (idx >> 4) & 15, jj = idx & 15;
            float acc = 0.f;
            #pragma unroll
            for (int l = 0; l < ORD; ++l) acc += sG[m][ii][l] * sG[have][l][jj];
            sG[have + m][ii][jj] = acc;
        }
        __syncthreads(); have += nn;
    }
    __syncthreads();

    // ---- local pass: wave 0 simulates 64 chunks (zero entry state) ----
    if (tid < 64) {
        float a[ORD], bb[ORD], uw[ORD], yr[ORD];
        #pragma unroll
        for (int l = 0; l < ORD; ++l) { a[l] = A_w[l]; bb[l] = B_w[l]; yr[l] = 0.f; }
        #pragma unroll
        for (int l = 0; l < ORD; ++l) uw[l] = u_s[tid][l];
        for (int k0 = 0; k0 < LCH; k0 += ORD) {
            #pragma unroll
            for (int kk = 0; kk < ORD; ++kk) {
                const int t = k0 + kk;
                float x = 0.f;
                #pragma unroll
                for (int s = 0; s < ORD; ++s) x += bb[15 - s] * uw[(kk + s) & 15];
                float y = x;    // add a[0]*y[t-1] LAST -> 1-FMA cross-step chain
                #pragma unroll
                for (int ii = ORD - 1; ii >= 1; --ii) y += a[ii] * yr[(kk - 1 - ii) & 15];
                y += a[0] * yr[(kk - 1) & 15];
                yr[kk] = y;
                y_s[tid][t] = y;
                uw[kk] = u_s[tid][t + ORD];
            }
        }
        #pragma unroll
        for (int l = 0; l < ORD; ++l) sdl[tid][l] = yr[15 - l];
    }
    __syncthreads();
    for (int idx = tid; idx < CPB * ORD; idx += 256)      // coalesced d write
        d_aos[cb * ORD + idx] = sdl[idx >> 4][idx & 15];

    cg::this_grid().sync();

    // ---- stage neighbor d (coalesced) ----
    for (int idx = tid; idx < (CPB + QT - 1) * ORD; idx += 256) {
        const int cpr = cb - QT + (idx >> 4);
        sd[idx >> 4][idx & 15] = (cpr >= 0) ? d_aos[cpr * ORD + (idx & 15)] : 0.f;
    }
    __syncthreads();

    // ---- phase A: S_c[j] = sum_m (G^m . d_{c-1-m})[j], 4 chunks/thread ----
    {
        const int jj = tid & 15, c0 = tid >> 4;
        float s0 = 0.f, s1 = 0.f, s2 = 0.f, s3 = 0.f;
        for (int m = 0; m < QT; ++m) {
            #pragma unroll
            for (int ii = 0; ii < ORD; ++ii) {
                const float g = sG[m][ii][jj];
                s0 += g * sd[c0      + QT - 1 - m][ii];
                s1 += g * sd[c0 + 16 + QT - 1 - m][ii];
                s2 += g * sd[c0 + 32 + QT - 1 - m][ii];
                s3 += g * sd[c0 + 48 + QT - 1 - m][ii];
            }
        }
        sS[c0][jj] = s0; sS[c0 + 16][jj] = s1; sS[c0 + 32][jj] = s2; sS[c0 + 48][jj] = s3;
    }
    __syncthreads();

    // ---- phase B fused with store: out = y_loc + V_k . S_c (float4) ----
    float4* out4 = (float4*)(out + base);
    #pragma unroll
    for (int it = 0; it < 4; ++it) {
        const int f = it * 256 + tid;            // float4 idx in [0,1024)
        const int row = f >> 4, k = (f & 15) * 4;
        float4 y = *(const float4*)&y_s[row][k];
        #pragma unroll
        for (int jj2 = 0; jj2 < ORD; ++jj2) {
            const float s = sS[row][jj2];
            const float4 vv = *(const float4*)&sV[jj2][k];
            y.x += vv.x * s; y.y += vv.y * s; y.z += vv.z * s; y.w += vv.w * s;
        }
        out4[f] = y;
    }
}

extern "C" void kernel_launch(void* const* d_in, const int* in_sizes, int n_in,
                              void* d_out, int out_size, void* d_ws, size_t ws_size,
                              hipStream_t stream) {
    const float* u = (const float*)d_in[0];
    const float* A = (const float*)d_in[1];
    const float* B = (const float*)d_in[2];
    float* out = (float*)d_out;
    float* dws = (float*)d_ws;
    void* args[] = {(void*)&u, (void*)&A, (void*)&B, (void*)&out, (void*)&dws};
    hipLaunchCooperativeKernel((const void*)k_fused, dim3(NB), dim3(256), args, 0, stream);
}

// Round 4
// 28.791 us; speedup vs baseline: 2.4977x; 2.4977x over previous
//
#include <hip/hip_runtime.h>

#define ORD 16
#define LCH 64
#define PCH 16384          // chunks; PCH*LCH = 2^20
#define NBS 256            // sim blocks (64 chunks each)
#define CPB 64             // chunks per k_fix block
#define QT  20             // scan warm-up depth (0.656^20 ~ 2e-4)

// ws float layout:
#define WS_D 0                       // d[c][i], AoS, PCH*16 floats
#define WS_G (PCH * ORD)             // G = M^64, 256 floats
#define WS_V (PCH * ORD + 256)       // V[j][k] = (a.M^k)[j], 16*64 floats

__global__ __launch_bounds__(64) void k_sim(const float* __restrict__ u,
                                            const float* __restrict__ A_w,
                                            const float* __restrict__ B_w,
                                            float* __restrict__ out,
                                            float* __restrict__ ws) {
    const int lane = threadIdx.x;
    const int blk  = blockIdx.x;

    if (blk >= NBS) {
        if (blk == NBS) {
            // ---- G = M^64 via 6 squarings (single 64-thread block) ----
            __shared__ float Ma[ORD][ORD + 1];
            #pragma unroll
            for (int p = 0; p < 4; ++p) {
                const int e = lane + 64 * p, i = e >> 4, j = e & 15;
                Ma[i][j] = (i == 0) ? A_w[j] : ((j == i - 1) ? 1.f : 0.f);
            }
            __syncthreads();
            for (int s = 0; s < 6; ++s) {
                float acc[4];
                #pragma unroll
                for (int p = 0; p < 4; ++p) {
                    const int e = lane + 64 * p, i = e >> 4, j = e & 15;
                    float v = 0.f;
                    #pragma unroll
                    for (int k = 0; k < ORD; ++k) v += Ma[i][k] * Ma[k][j];
                    acc[p] = v;
                }
                __syncthreads();
                #pragma unroll
                for (int p = 0; p < 4; ++p) {
                    const int e = lane + 64 * p;
                    Ma[e >> 4][e & 15] = acc[p];
                }
                __syncthreads();
            }
            #pragma unroll
            for (int p = 0; p < 4; ++p) {
                const int e = lane + 64 * p;
                ws[WS_G + e] = Ma[e >> 4][e & 15];
            }
        } else {
            // ---- V table: v_0 = a, v_{k+1}[j] = v[0]*a[j] + v[j+1] ----
            if (lane < ORD) {
                const float aj = A_w[lane];
                float v = aj;
                for (int k = 0; k < LCH; ++k) {
                    ws[WS_V + lane * LCH + k] = v;
                    const float v0 = __shfl(v, 0, 16);
                    const float vn = __shfl_down(v, 1, 16);
                    v = v0 * aj + ((lane < ORD - 1) ? vn : 0.f);
                }
            }
        }
        return;
    }

    // ---- local sim: 64 chunks per block, one per lane ----
    __shared__ float u_s[64][81];     // stride 81 (odd*... conflict-free reads)
    __shared__ float y_s[64][65];     // stride 65 -> conflict-free scalar r/w
    __shared__ float sdl[64][17];
    const int cb = blk * 64;
    const long base = (long)cb * LCH;

    const float* ug = u + base;
    for (int g4 = lane; g4 < (64 * LCH + ORD) / 4; g4 += 64) {
        const float4 v = ((const float4*)ug)[g4];
        const int g = g4 * 4;
        #pragma unroll
        for (int e = 0; e < 4; ++e) {
            const int idx = g + e, row = idx >> 6, col = idx & 63;
            const float f = (e == 0) ? v.x : (e == 1) ? v.y : (e == 2) ? v.z : v.w;
            if (row < 64) u_s[row][col] = f;
            if (col < ORD && row >= 1) u_s[row - 1][64 + col] = f;
        }
    }
    float a[ORD], b[ORD];
    #pragma unroll
    for (int i = 0; i < ORD; ++i) { a[i] = A_w[i]; b[i] = B_w[i]; }
    __syncthreads();

    float uw[ORD], yr[ORD];
    #pragma unroll
    for (int j = 0; j < ORD; ++j) uw[j] = u_s[lane][j];
    #pragma unroll
    for (int i = 0; i < ORD; ++i) yr[i] = 0.f;

    for (int k0 = 0; k0 < LCH; k0 += ORD) {
        #pragma unroll
        for (int kk = 0; kk < ORD; ++kk) {
            const int t = k0 + kk;
            float x = 0.f;
            #pragma unroll
            for (int s = 0; s < ORD; ++s) x += b[15 - s] * uw[(kk + s) & 15];
            float y = x;    // a[0]*y[t-1] added LAST -> 1-FMA cross-step chain
            #pragma unroll
            for (int i = ORD - 1; i >= 1; --i) y += a[i] * yr[(kk - 1 - i) & 15];
            y += a[0] * yr[(kk - 1) & 15];
            yr[kk] = y;
            y_s[lane][t] = y;
            uw[kk] = u_s[lane][t + ORD];
        }
    }
    #pragma unroll
    for (int i = 0; i < ORD; ++i) sdl[lane][i] = yr[15 - i];
    __syncthreads();
    for (int idx = lane; idx < 64 * ORD; idx += 64)          // coalesced d (AoS)
        ws[WS_D + cb * ORD + idx] = sdl[idx >> 4][idx & 15];
    for (int g = lane; g < 64 * LCH; g += 64)                // coalesced y_loc
        out[base + g] = y_s[g >> 6][g & 63];
}

__global__ __launch_bounds__(256) void k_fix(float* __restrict__ out,
                                             const float* __restrict__ ws) {
    __shared__ float sGm[ORD][17];
    __shared__ float sV[ORD][LCH];            // contiguous -> float4 reads
    __shared__ float sd[CPB + QT][17];
    __shared__ float sS[CPB][17];
    const int tid = threadIdx.x;
    const int cb = blockIdx.x * CPB;

    sGm[tid >> 4][tid & 15] = ws[WS_G + tid];
    ((float4*)sV)[tid] = ((const float4*)(ws + WS_V))[tid];
    for (int idx = tid; idx < (CPB + QT) * ORD; idx += 256) {
        const int r = idx >> 4, j = idx & 15;
        const int cpr = cb - QT + r;
        sd[r][j] = (cpr >= 0) ? ws[WS_D + cpr * ORD + j] : 0.f;
    }
    __syncthreads();

    // ---- scan: S_{c+1} = G*S_c + d_c ; wave w owns chunks [16w, 16w+16) ----
    {
        const int l = tid & 63, w = tid >> 6;
        const int j = l & 15, q = l >> 4;
        const float g0 = sGm[j][4 * q + 0], g1 = sGm[j][4 * q + 1];
        const float g2 = sGm[j][4 * q + 2], g3 = sGm[j][4 * q + 3];
        const int s0 = 4 * q;             // gather sources (loop-invariant)
        const int c0 = w * 16;
        float S = 0.f;                    // ~= S_{c0-QT}
        for (int lc = c0 - QT; lc < c0 + 16; ++lc) {
            if (lc >= c0 && l < 16) sS[lc][j] = S;      // S == S_lc here
            float p = g0 * __shfl(S, s0, 16) + g1 * __shfl(S, s0 + 1, 16)
                    + g2 * __shfl(S, s0 + 2, 16) + g3 * __shfl(S, s0 + 3, 16);
            p += __shfl_xor(p, 16);
            p += __shfl_xor(p, 32);
            S = p + sd[lc + QT][j];       // S_{lc+1}
        }
    }
    __syncthreads();

    // ---- phase B: out[c*64+k] = y_loc + V_k . S_c (float4 RMW) ----
    float4* out4 = (float4*)(out + (long)cb * LCH);
    const float4* sV4 = (const float4*)sV;
    #pragma unroll
    for (int it = 0; it < 4; ++it) {
        const int f = it * 256 + tid;
        const int row = f >> 4, k4 = f & 15;
        float4 y = out4[f];
        #pragma unroll
        for (int j = 0; j < ORD; ++j) {
            const float s = sS[row][j];
            const float4 vv = sV4[j * 16 + k4];
            y.x += vv.x * s; y.y += vv.y * s; y.z += vv.z * s; y.w += vv.w * s;
        }
        out4[f] = y;
    }
}

extern "C" void kernel_launch(void* const* d_in, const int* in_sizes, int n_in,
                              void* d_out, int out_size, void* d_ws, size_t ws_size,
                              hipStream_t stream) {
    const float* u = (const float*)d_in[0];
    const float* A = (const float*)d_in[1];
    const float* B = (const float*)d_in[2];
    float* out = (float*)d_out;
    float* ws  = (float*)d_ws;
    k_sim<<<NBS + 2, 64, 0, stream>>>(u, A, B, out, ws);
    k_fix<<<PCH / CPB, 256, 0, stream>>>(out, ws);
}

// Round 5
// 28.042 us; speedup vs baseline: 2.5644x; 1.0267x over previous
//
#include <hip/hip_runtime.h>

#define ORD 16
#define LCH 64
#define PCH 16384          // chunks; PCH*LCH = 2^20
#define NB  256            // blocks; CPB own chunks each
#define CPB 64
#define QT  20             // warm-up depth (||M^64||^20 ~ 0.656^20 ~ 2e-4)
#define WCH (CPB + QT)     // window chunks per block = 84

__global__ __launch_bounds__(256) void k_arx(const float* __restrict__ u,
                                             const float* __restrict__ A_w,
                                             const float* __restrict__ B_w,
                                             float* __restrict__ out) {
    __shared__ float u_s[WCH][81];       // 27.2 KB (81 = 17 mod 32: 2-way max)
    __shared__ float y_s[CPB][65];       // 16.6 KB, odd stride conflict-free
    __shared__ float sR[16][ORD][17];    // M^r, r=0..15 (pad 17)
    __shared__ float sM[3][ORD][17];     // M^16, M^32, G=M^64
    __shared__ float sW[4][ORD];         // w_q = a . M^(16q)
    __shared__ float sV[ORD][LCH];       // V[j][k] = (a.M^k)[j]
    __shared__ float sGm[ORD][17];       // G
    __shared__ float sd[WCH][17];        // window-chunk end states
    __shared__ float sS[CPB][17];        // own-chunk entry states

    const int tid = threadIdx.x;
    const int cb  = blockIdx.x * CPB;

    // ---- stage u for window chunks [cb-QT, cb+CPB), cols 0..79 ----
    const long gstart = ((long)cb - QT) * LCH;
    for (int g4 = tid; g4 < (WCH * LCH + ORD) / 4; g4 += 256) {
        if (gstart + g4 * 4 >= 0) {     // block 0: skip pre-signal rows
            const float4 v = *(const float4*)(u + gstart + g4 * 4);
            const int g = g4 * 4;
            #pragma unroll
            for (int e = 0; e < 4; ++e) {
                const int idx = g + e, row = idx >> 6, col = idx & 63;
                const float f = (e == 0) ? v.x : (e == 1) ? v.y : (e == 2) ? v.z : v.w;
                if (row < WCH) u_s[row][col] = f;
                if (col < ORD && row >= 1 && row <= WCH) u_s[row - 1][64 + col] = f;
            }
        }
    }

    // ---- tables (per block, in LDS) ----
    {
        const int i = tid >> 4, j = tid & 15;
        sR[0][i][j] = (i == j) ? 1.f : 0.f;
        sR[1][i][j] = (i == 0) ? A_w[j] : ((j == i - 1) ? 1.f : 0.f);
        if (tid < ORD) sW[0][tid] = A_w[tid];
    }
    __syncthreads();
    int have = 1;
    while (have < 15) {                  // M^2..M^15 by doubling
        const int nn = (have < 15 - have) ? have : (15 - have);
        for (int idx = tid; idx < nn * 256; idx += 256) {
            const int m = (idx >> 8) + 1, ii = (idx >> 4) & 15, jj = idx & 15;
            float acc = 0.f;
            #pragma unroll
            for (int l = 0; l < ORD; ++l) acc += sR[have][ii][l] * sR[m][l][jj];
            sR[have + m][ii][jj] = acc;
        }
        __syncthreads();
        have += nn;
    }
    {
        const int i = tid >> 4, j = tid & 15;
        float acc = 0.f;
        #pragma unroll
        for (int l = 0; l < ORD; ++l) acc += sR[15][i][l] * sR[1][l][j];
        sM[0][i][j] = acc;               // M^16
    }
    __syncthreads();
    {
        const int i = tid >> 4, j = tid & 15;
        float acc = 0.f;
        #pragma unroll
        for (int l = 0; l < ORD; ++l) acc += sM[0][i][l] * sM[0][l][j];
        sM[1][i][j] = acc;               // M^32
    }
    __syncthreads();
    {
        const int i = tid >> 4, j = tid & 15;
        float acc = 0.f;
        #pragma unroll
        for (int l = 0; l < ORD; ++l) acc += sM[1][i][l] * sM[1][l][j];
        sM[2][i][j] = acc;               // G = M^64
    }
    __syncthreads();
    for (int q = 0; q < 3; ++q) {        // w_{q+1} = w_q . M^16
        if (tid < ORD) {
            float acc = 0.f;
            #pragma unroll
            for (int l = 0; l < ORD; ++l) acc += sW[q][l] * sM[0][l][tid];
            sW[q + 1][tid] = acc;
        }
        __syncthreads();
    }
    for (int idx = tid; idx < ORD * LCH; idx += 256) {   // V[j][k] = w_q . M^r
        const int k = idx >> 4, jj = idx & 15, q = k >> 4, r = k & 15;
        float acc = 0.f;
        #pragma unroll
        for (int l = 0; l < ORD; ++l) acc += sW[q][l] * sR[r][l][jj];
        sV[jj][k] = acc;
    }
    sGm[tid >> 4][tid & 15] = sM[2][tid >> 4][tid & 15];
    __syncthreads();

    // ---- local sim: lanes 0..83 own window chunk tid (zero entry state) ----
    {
        const int gchunk = cb - QT + tid;
        float yr[ORD];
        #pragma unroll
        for (int i = 0; i < ORD; ++i) yr[i] = 0.f;
        if (tid < WCH && gchunk >= 0) {
            float a[ORD], bb[ORD], uw[ORD];
            #pragma unroll
            for (int i = 0; i < ORD; ++i) { a[i] = A_w[i]; bb[i] = B_w[i]; }
            #pragma unroll
            for (int j = 0; j < ORD; ++j) uw[j] = u_s[tid][j];
            const bool own = (tid >= QT);
            for (int k0 = 0; k0 < LCH; k0 += ORD) {
                #pragma unroll
                for (int kk = 0; kk < ORD; ++kk) {
                    const int t = k0 + kk;
                    float x = 0.f;
                    #pragma unroll
                    for (int s = 0; s < ORD; ++s) x += bb[15 - s] * uw[(kk + s) & 15];
                    float y = x;   // a[0]*y[t-1] added LAST -> 1-FMA chain
                    #pragma unroll
                    for (int i = ORD - 1; i >= 1; --i) y += a[i] * yr[(kk - 1 - i) & 15];
                    y += a[0] * yr[(kk - 1) & 15];
                    yr[kk] = y;
                    if (own) y_s[tid - QT][t] = y;
                    uw[kk] = u_s[tid][t + ORD];
                }
            }
        }
        if (tid < WCH) {
            #pragma unroll
            for (int i = 0; i < ORD; ++i) sd[tid][i] = yr[15 - i];
        }
    }
    __syncthreads();

    // ---- scan: S_{c+1} = G*S_c + d_c ; wave w owns chunks [16w,16w+16) ----
    {
        const int l = tid & 63, w = tid >> 6;
        const int j = l & 15, q = l >> 4;
        const float g0 = sGm[j][4 * q + 0], g1 = sGm[j][4 * q + 1];
        const float g2 = sGm[j][4 * q + 2], g3 = sGm[j][4 * q + 3];
        const int s0 = 4 * q;
        const int c0 = w * 16;
        float S = 0.f;                   // ~= S at entry of chunk c0-QT
        for (int lc = c0 - QT; lc < c0 + 16; ++lc) {
            if (lc >= c0 && l < 16) sS[lc][j] = S;
            float p = g0 * __shfl(S, s0, 16) + g1 * __shfl(S, s0 + 1, 16)
                    + g2 * __shfl(S, s0 + 2, 16) + g3 * __shfl(S, s0 + 3, 16);
            p += __shfl_xor(p, 16);
            p += __shfl_xor(p, 32);
            S = p + sd[lc + QT][j];
        }
    }
    __syncthreads();

    // ---- fused correction + store: out = y_loc + V_k . S_c ----
    const long base = (long)cb * LCH;
    #pragma unroll
    for (int it = 0; it < 16; ++it) {
        const int g = it * 256 + tid;     // 0..4095
        const int o = g >> 6, t = g & 63; // o uniform per wave -> sS broadcast
        float y = y_s[o][t];
        #pragma unroll
        for (int j = 0; j < ORD; ++j) y += sV[j][t] * sS[o][j];
        out[base + g] = y;
    }
}

extern "C" void kernel_launch(void* const* d_in, const int* in_sizes, int n_in,
                              void* d_out, int out_size, void* d_ws, size_t ws_size,
                              hipStream_t stream) {
    const float* u = (const float*)d_in[0];
    const float* A = (const float*)d_in[1];
    const float* B = (const float*)d_in[2];
    float* out = (float*)d_out;
    k_arx<<<NB, 256, 0, stream>>>(u, A, B, out);
}

// Round 6
// 22.499 us; speedup vs baseline: 3.1963x; 1.2464x over previous
//
#include <hip/hip_runtime.h>

#define ORD 16
#define LCH 64
#define PCH 16384          // chunks; PCH*LCH = 2^20
#define NB  256            // blocks; CPB own chunks each
#define CPB 64
#define QT  16             // warm-up chunks (0.6561^16*8 ~ 0.009 trunc err)
#define WCH (CPB + QT)     // 80 window chunks per block
#define NG  (WCH / 4)      // 20 4-chunk scan groups
#define USTR 84            // u_s row stride: 4*odd -> conflict-free b128
#define YSTR 68            // y_s row stride: 4*odd

__global__ __launch_bounds__(256) void k_arx(const float* __restrict__ u,
                                             const float* __restrict__ A_w,
                                             const float* __restrict__ B_w,
                                             float* __restrict__ out) {
    __shared__ float u_s[WCH][USTR];     // 26.9 KB
    __shared__ float y_s[CPB][YSTR];     // 17.4 KB
    __shared__ float sR[16][ORD][17];    // M^r, r=0..15
    __shared__ float sM16[ORD][17], sM32[ORD][17];
    __shared__ float sG1[ORD][17], sG2[ORD][17], sG3[ORD][17], sG4[ORD][17];
    __shared__ float sW[4][ORD];         // w_q = a . M^(16q)
    __shared__ float sV[ORD][LCH];       // V[j][k] = (a.M^k)[j]
    __shared__ float sd[WCH][17];        // window-chunk end states
    __shared__ float sF[NG][17];         // 4-group inhomogeneous terms
    __shared__ float sS[CPB][17];        // own-chunk entry states

    const int tid = threadIdx.x;
    const int cb  = blockIdx.x * CPB;
    const long gstart = ((long)cb - QT) * LCH;

    // ---- stage u (b128 LDS writes, coalesced b128 global reads) ----
    for (int g4 = tid; g4 < WCH * (LCH / 4); g4 += 256) {
        const long gi = gstart + 4 * g4;
        if (gi >= 0) {
            const float4 v = *(const float4*)(u + gi);
            *(float4*)&u_s[g4 >> 4][(g4 & 15) * 4] = v;
        }
    }
    for (int idx = tid; idx < WCH * 4; idx += 256) {   // tail cols 64..79
        const int row = idx >> 2, m = idx & 3;
        const long gi = gstart + (long)(row + 1) * LCH + 4 * m;
        if (gi >= 0) {
            const float4 v = *(const float4*)(u + gi);
            *(float4*)&u_s[row][64 + 4 * m] = v;
        }
    }

    // ---- tables ----
    const int ti = tid >> 4, tj = tid & 15;
    sR[0][ti][tj] = (ti == tj) ? 1.f : 0.f;
    sR[1][ti][tj] = (ti == 0) ? A_w[tj] : ((tj == ti - 1) ? 1.f : 0.f);
    if (tid < ORD) sW[0][tid] = A_w[tid];
    __syncthreads();
    int have = 1;
    while (have < 15) {                  // M^2..M^15 by doubling
        const int nn = (have < 15 - have) ? have : (15 - have);
        for (int idx = tid; idx < nn * 256; idx += 256) {
            const int m = (idx >> 8) + 1, ii = (idx >> 4) & 15, jj = idx & 15;
            float acc = 0.f;
            #pragma unroll
            for (int l = 0; l < ORD; ++l) acc += sR[have][ii][l] * sR[m][l][jj];
            sR[have + m][ii][jj] = acc;
        }
        __syncthreads();
        have += nn;
    }
    {   float acc = 0.f;                 // M^16
        #pragma unroll
        for (int l = 0; l < ORD; ++l) acc += sR[15][ti][l] * sR[1][l][tj];
        sM16[ti][tj] = acc; }
    __syncthreads();
    {   float acc = 0.f;                 // M^32 ; sW1
        #pragma unroll
        for (int l = 0; l < ORD; ++l) acc += sM16[ti][l] * sM16[l][tj];
        sM32[ti][tj] = acc;
        if (tid < ORD) {
            float w = 0.f;
            #pragma unroll
            for (int l = 0; l < ORD; ++l) w += sW[0][l] * sM16[l][tid];
            sW[1][tid] = w;
        } }
    __syncthreads();
    {   float acc = 0.f;                 // G = M^64 ; sW2
        #pragma unroll
        for (int l = 0; l < ORD; ++l) acc += sM32[ti][l] * sM32[l][tj];
        sG1[ti][tj] = acc;
        if (tid < ORD) {
            float w = 0.f;
            #pragma unroll
            for (int l = 0; l < ORD; ++l) w += sW[1][l] * sM16[l][tid];
            sW[2][tid] = w;
        } }
    __syncthreads();
    {   float acc = 0.f;                 // G^2 ; sW3
        #pragma unroll
        for (int l = 0; l < ORD; ++l) acc += sG1[ti][l] * sG1[l][tj];
        sG2[ti][tj] = acc;
        if (tid < ORD) {
            float w = 0.f;
            #pragma unroll
            for (int l = 0; l < ORD; ++l) w += sW[2][l] * sM16[l][tid];
            sW[3][tid] = w;
        } }
    __syncthreads();
    {   float a3 = 0.f, a4 = 0.f;        // G^3, G^4
        #pragma unroll
        for (int l = 0; l < ORD; ++l) {
            a3 += sG2[ti][l] * sG1[l][tj];
            a4 += sG2[ti][l] * sG2[l][tj];
        }
        sG3[ti][tj] = a3;
        sG4[ti][tj] = a4; }
    for (int idx = tid; idx < ORD * LCH; idx += 256) {   // V[j][k] = w_q . M^r
        const int k = idx >> 4, jj = idx & 15, q = k >> 4, r = k & 15;
        float acc = 0.f;
        #pragma unroll
        for (int l = 0; l < ORD; ++l) acc += sW[q][l] * sR[r][l][jj];
        sV[jj][k] = acc;
    }
    __syncthreads();

    // ---- local sim: lanes 0..79 own window chunk tid, zero entry state ----
    {
        const int gchunk = cb - QT + tid;
        float yr[ORD];
        #pragma unroll
        for (int i = 0; i < ORD; ++i) yr[i] = 0.f;
        if (tid < WCH && gchunk >= 0) {
            float a[ORD], bb[ORD], ucur[ORD], unext[ORD];
            #pragma unroll
            for (int i = 0; i < ORD; ++i) { a[i] = A_w[i]; bb[i] = B_w[i]; }
            #pragma unroll
            for (int m = 0; m < 4; ++m)
                *(float4*)&ucur[4 * m] = *(const float4*)&u_s[tid][4 * m];
            for (int k0 = 0; k0 < LCH; k0 += ORD) {
                #pragma unroll
                for (int m = 0; m < 4; ++m)
                    *(float4*)&unext[4 * m] = *(const float4*)&u_s[tid][k0 + 16 + 4 * m];
                #pragma unroll
                for (int kk = 0; kk < ORD; ++kk) {
                    float x = 0.f;
                    #pragma unroll
                    for (int s = 0; s < ORD; ++s) {
                        const float uv = (kk + s < 16) ? ucur[kk + s] : unext[kk + s - 16];
                        x += bb[15 - s] * uv;
                    }
                    float y = x;   // a[0]*y[t-1] added LAST -> 1-FMA chain
                    #pragma unroll
                    for (int i = ORD - 1; i >= 1; --i) y += a[i] * yr[(kk - 1 - i) & 15];
                    y += a[0] * yr[(kk - 1) & 15];
                    yr[kk] = y;
                }
                if (tid >= QT) {   // own chunk: save local y (b128)
                    #pragma unroll
                    for (int m = 0; m < 4; ++m)
                        *(float4*)&y_s[tid - QT][k0 + 4 * m] = *(const float4*)&yr[4 * m];
                }
                #pragma unroll
                for (int m = 0; m < ORD; ++m) ucur[m] = unext[m];
            }
        }
        if (tid < WCH) {
            #pragma unroll
            for (int i = 0; i < ORD; ++i) sd[tid][i] = yr[15 - i];
        }
    }
    __syncthreads();

    // ---- f-groups: f_g = G3.d[4g] + G2.d[4g+1] + G1.d[4g+2] + d[4g+3] ----
    for (int idx = tid; idx < NG * ORD; idx += 256) {
        const int g = idx >> 4, jj = idx & 15;
        float acc = sd[4 * g + 3][jj];
        #pragma unroll
        for (int i = 0; i < ORD; ++i) {
            acc += sG3[jj][i] * sd[4 * g][i];
            acc += sG2[jj][i] * sd[4 * g + 1][i];
            acc += sG1[jj][i] * sd[4 * g + 2][i];
        }
        sF[g][jj] = acc;
    }
    __syncthreads();

    // ---- blocked scan: S_{c+4} = G4.S_c + f ; 8 iters per wave ----
    {
        const int l = tid & 63, w = tid >> 6;
        const int j = l & 15, q = l >> 4;
        const float g0 = sG4[j][4 * q + 0], g1 = sG4[j][4 * q + 1];
        const float g2 = sG4[j][4 * q + 2], g3 = sG4[j][4 * q + 3];
        float S = 0.f;                   // ~= entry state of window row 16w
        #pragma unroll
        for (int i = 0; i < 8; ++i) {
            if (i >= 4 && l < 16) sS[16 * w + 4 * (i - 4)][j] = S;
            float p = g0 * __shfl(S, 4 * q + 0, 16) + g1 * __shfl(S, 4 * q + 1, 16)
                    + g2 * __shfl(S, 4 * q + 2, 16) + g3 * __shfl(S, 4 * q + 3, 16);
            p += __shfl_xor(p, 16);
            p += __shfl_xor(p, 32);
            S = p + sF[4 * w + i][j];
        }
    }
    // ---- reconstruct S at c%4 != 0 (data-parallel, 3 rounds) ----
    #pragma unroll
    for (int r = 1; r <= 3; ++r) {
        __syncthreads();
        const int g = tid >> 4, jj = tid & 15;
        float acc = sd[16 + 4 * g + r - 1][jj];
        #pragma unroll
        for (int i = 0; i < ORD; ++i) acc += sG1[jj][i] * sS[4 * g + r - 1][i];
        sS[4 * g + r][jj] = acc;
    }
    __syncthreads();

    // ---- correction + store: out = y_loc + V_k . S_c (b128 / dwordx4) ----
    float4* out4 = (float4*)(out + (long)cb * LCH);
    #pragma unroll
    for (int it = 0; it < 4; ++it) {
        const int f = it * 256 + tid;
        const int row = f >> 4, k4 = f & 15;
        float4 y = *(const float4*)&y_s[row][4 * k4];
        #pragma unroll
        for (int jj = 0; jj < ORD; ++jj) {
            const float s = sS[row][jj];
            const float4 vv = *(const float4*)&sV[jj][4 * k4];
            y.x += vv.x * s; y.y += vv.y * s; y.z += vv.z * s; y.w += vv.w * s;
        }
        out4[f] = y;
    }
}

extern "C" void kernel_launch(void* const* d_in, const int* in_sizes, int n_in,
                              void* d_out, int out_size, void* d_ws, size_t ws_size,
                              hipStream_t stream) {
    const float* u = (const float*)d_in[0];
    const float* A = (const float*)d_in[1];
    const float* B = (const float*)d_in[2];
    float* out = (float*)d_out;
    k_arx<<<NB, 256, 0, stream>>>(u, A, B, out);
}

// Round 7
// 21.320 us; speedup vs baseline: 3.3731x; 1.0553x over previous
//
#include <hip/hip_runtime.h>

#define ORD 16
#define LCH 64
#define PCH 16384          // chunks; PCH*LCH = 2^20
#define NB  256            // blocks; CPB own chunks each
#define CPB 64
#define QT  16             // warm-up chunks (0.6561^16*8 ~ 0.009 trunc err)
#define WCH (CPB + QT)     // 80 window chunks per block
#define NG  (WCH / 4)      // 20 4-chunk scan groups
#define USTR 84            // u_s/xs row stride: 4*odd -> b128 conflict-light
#define YSTR 68            // y_s row stride: 4*odd

__global__ __launch_bounds__(256) void k_arx(const float* __restrict__ u,
                                             const float* __restrict__ A_w,
                                             const float* __restrict__ B_w,
                                             float* __restrict__ out) {
    __shared__ float u_s[WCH][USTR];     // 26.9 KB
    __shared__ float xs[WCH][USTR];      // 26.9 KB  (FIR output)
    __shared__ float y_s[CPB][YSTR];     // 17.4 KB
    __shared__ float sR[16][ORD][17];    // M^r, r=0..15
    __shared__ float sM16[ORD][17], sM32[ORD][17];
    __shared__ float sG1[ORD][17], sG2[ORD][17], sG3[ORD][17], sG4[ORD][17];
    __shared__ float sW[4][ORD];         // w_q = a . M^(16q)
    __shared__ float sV[ORD][LCH];       // V[j][k] = (a.M^k)[j]
    __shared__ float sd[WCH][17];        // window-chunk end states
    __shared__ float sF[NG][17];         // 4-group inhomogeneous terms
    __shared__ float sS[CPB][17];        // own-chunk entry states

    const int tid = threadIdx.x;
    const int cb  = blockIdx.x * CPB;
    const long gstart = ((long)cb - QT) * LCH;

    // ---- stage u (b128 LDS writes, coalesced b128 global reads) ----
    for (int g4 = tid; g4 < WCH * (LCH / 4); g4 += 256) {
        const long gi = gstart + 4 * g4;
        if (gi >= 0) {
            const float4 v = *(const float4*)(u + gi);
            *(float4*)&u_s[g4 >> 4][(g4 & 15) * 4] = v;
        }
    }
    for (int idx = tid; idx < WCH * 4; idx += 256) {   // tail cols 64..79
        const int row = idx >> 2, m = idx & 3;
        const long gi = gstart + (long)(row + 1) * LCH + 4 * m;
        if (gi >= 0) {
            const float4 v = *(const float4*)(u + gi);
            *(float4*)&u_s[row][64 + 4 * m] = v;
        }
    }

    // ---- tables ----
    const int ti = tid >> 4, tj = tid & 15;
    sR[0][ti][tj] = (ti == tj) ? 1.f : 0.f;
    sR[1][ti][tj] = (ti == 0) ? A_w[tj] : ((tj == ti - 1) ? 1.f : 0.f);
    if (tid < ORD) sW[0][tid] = A_w[tid];
    __syncthreads();
    int have = 1;
    while (have < 15) {                  // M^2..M^15 by doubling
        const int nn = (have < 15 - have) ? have : (15 - have);
        for (int idx = tid; idx < nn * 256; idx += 256) {
            const int m = (idx >> 8) + 1, ii = (idx >> 4) & 15, jj = idx & 15;
            float acc = 0.f;
            #pragma unroll
            for (int l = 0; l < ORD; ++l) acc += sR[have][ii][l] * sR[m][l][jj];
            sR[have + m][ii][jj] = acc;
        }
        __syncthreads();
        have += nn;
    }
    {   float acc = 0.f;                 // M^16
        #pragma unroll
        for (int l = 0; l < ORD; ++l) acc += sR[15][ti][l] * sR[1][l][tj];
        sM16[ti][tj] = acc; }
    __syncthreads();
    {   float acc = 0.f;                 // M^32 ; sW1
        #pragma unroll
        for (int l = 0; l < ORD; ++l) acc += sM16[ti][l] * sM16[l][tj];
        sM32[ti][tj] = acc;
        if (tid < ORD) {
            float w = 0.f;
            #pragma unroll
            for (int l = 0; l < ORD; ++l) w += sW[0][l] * sM16[l][tid];
            sW[1][tid] = w;
        } }
    __syncthreads();
    {   float acc = 0.f;                 // G = M^64 ; sW2
        #pragma unroll
        for (int l = 0; l < ORD; ++l) acc += sM32[ti][l] * sM32[l][tj];
        sG1[ti][tj] = acc;
        if (tid < ORD) {
            float w = 0.f;
            #pragma unroll
            for (int l = 0; l < ORD; ++l) w += sW[1][l] * sM16[l][tid];
            sW[2][tid] = w;
        } }
    __syncthreads();
    {   float acc = 0.f;                 // G^2 ; sW3
        #pragma unroll
        for (int l = 0; l < ORD; ++l) acc += sG1[ti][l] * sG1[l][tj];
        sG2[ti][tj] = acc;
        if (tid < ORD) {
            float w = 0.f;
            #pragma unroll
            for (int l = 0; l < ORD; ++l) w += sW[2][l] * sM16[l][tid];
            sW[3][tid] = w;
        } }
    __syncthreads();
    {   float a3 = 0.f, a4 = 0.f;        // G^3, G^4
        #pragma unroll
        for (int l = 0; l < ORD; ++l) {
            a3 += sG2[ti][l] * sG1[l][tj];
            a4 += sG2[ti][l] * sG2[l][tj];
        }
        sG3[ti][tj] = a3;
        sG4[ti][tj] = a4; }
    for (int idx = tid; idx < ORD * LCH; idx += 256) {   // V[j][k] = w_q . M^r
        const int k = idx >> 4, jj = idx & 15, q = k >> 4, r = k & 15;
        float acc = 0.f;
        #pragma unroll
        for (int l = 0; l < ORD; ++l) acc += sW[q][l] * sR[r][l][jj];
        sV[jj][k] = acc;
    }
    __syncthreads();

    // ---- FIR (data-parallel, all 256 threads): xs[w][t] = sum b.u ----
    {
        float bb[ORD];
        #pragma unroll
        for (int i = 0; i < ORD; ++i) bb[i] = B_w[i];
        for (int idx = tid; idx < WCH * 4; idx += 256) {
            const int w = idx >> 2, t0 = (idx & 3) * 16;
            float uu[32];
            #pragma unroll
            for (int m = 0; m < 8; ++m)
                *(float4*)&uu[4 * m] = *(const float4*)&u_s[w][t0 + 4 * m];
            float xv[16];
            #pragma unroll
            for (int kk = 0; kk < 16; ++kk) {
                float x = 0.f;
                #pragma unroll
                for (int s = 0; s < ORD; ++s) x += bb[15 - s] * uu[kk + s];
                xv[kk] = x;
            }
            #pragma unroll
            for (int m = 0; m < 4; ++m)
                *(float4*)&xs[w][t0 + 4 * m] = *(const float4*)&xv[4 * m];
        }
    }
    __syncthreads();

    // ---- serial sim (IIR only): lanes 0..79 own window chunk tid ----
    {
        const int gchunk = cb - QT + tid;
        float yr[ORD];
        #pragma unroll
        for (int i = 0; i < ORD; ++i) yr[i] = 0.f;
        if (tid < WCH && gchunk >= 0) {
            float a[ORD], xv[ORD];
            #pragma unroll
            for (int i = 0; i < ORD; ++i) a[i] = A_w[i];
            for (int k0 = 0; k0 < LCH; k0 += ORD) {
                #pragma unroll
                for (int m = 0; m < 4; ++m)
                    *(float4*)&xv[4 * m] = *(const float4*)&xs[tid][k0 + 4 * m];
                #pragma unroll
                for (int kk = 0; kk < ORD; ++kk) {
                    float y = xv[kk];   // a[0]*y[t-1] added LAST -> 1-FMA chain
                    #pragma unroll
                    for (int i = ORD - 1; i >= 1; --i) y += a[i] * yr[(kk - 1 - i) & 15];
                    y += a[0] * yr[(kk - 1) & 15];
                    yr[kk] = y;
                }
                if (tid >= QT) {
                    #pragma unroll
                    for (int m = 0; m < 4; ++m)
                        *(float4*)&y_s[tid - QT][k0 + 4 * m] = *(const float4*)&yr[4 * m];
                }
            }
        }
        if (tid < WCH) {
            #pragma unroll
            for (int i = 0; i < ORD; ++i) sd[tid][i] = yr[15 - i];
        }
    }
    __syncthreads();

    // ---- f-groups: f_g = G3.d[4g] + G2.d[4g+1] + G1.d[4g+2] + d[4g+3] ----
    for (int idx = tid; idx < NG * ORD; idx += 256) {
        const int g = idx >> 4, jj = idx & 15;
        float acc = sd[4 * g + 3][jj];
        #pragma unroll
        for (int i = 0; i < ORD; ++i) {
            acc += sG3[jj][i] * sd[4 * g][i];
            acc += sG2[jj][i] * sd[4 * g + 1][i];
            acc += sG1[jj][i] * sd[4 * g + 2][i];
        }
        sF[g][jj] = acc;
    }
    __syncthreads();

    // ---- blocked scan: S_{c+4} = G4.S_c + f ; 8 iters per wave ----
    {
        const int l = tid & 63, w = tid >> 6;
        const int j = l & 15, q = l >> 4;
        const float g0 = sG4[j][4 * q + 0], g1 = sG4[j][4 * q + 1];
        const float g2 = sG4[j][4 * q + 2], g3 = sG4[j][4 * q + 3];
        float S = 0.f;                   // ~= entry state of window row 16w
        #pragma unroll
        for (int i = 0; i < 8; ++i) {
            if (i >= 4 && l < 16) sS[16 * w + 4 * (i - 4)][j] = S;
            float p = g0 * __shfl(S, 4 * q + 0, 16) + g1 * __shfl(S, 4 * q + 1, 16)
                    + g2 * __shfl(S, 4 * q + 2, 16) + g3 * __shfl(S, 4 * q + 3, 16);
            p += __shfl_xor(p, 16);
            p += __shfl_xor(p, 32);
            S = p + sF[4 * w + i][j];
        }
    }
    // ---- reconstruct S at c%4 != 0 (data-parallel, 3 rounds) ----
    #pragma unroll
    for (int r = 1; r <= 3; ++r) {
        __syncthreads();
        const int g = tid >> 4, jj = tid & 15;
        float acc = sd[16 + 4 * g + r - 1][jj];
        #pragma unroll
        for (int i = 0; i < ORD; ++i) acc += sG1[jj][i] * sS[4 * g + r - 1][i];
        sS[4 * g + r][jj] = acc;
    }
    __syncthreads();

    // ---- correction + store: out = y_loc + V_k . S_c (b128 / dwordx4) ----
    float4* out4 = (float4*)(out + (long)cb * LCH);
    #pragma unroll
    for (int it = 0; it < 4; ++it) {
        const int f = it * 256 + tid;
        const int row = f >> 4, k4 = f & 15;
        float4 y = *(const float4*)&y_s[row][4 * k4];
        #pragma unroll
        for (int jj = 0; jj < ORD; ++jj) {
            const float s = sS[row][jj];
            const float4 vv = *(const float4*)&sV[jj][4 * k4];
            y.x += vv.x * s; y.y += vv.y * s; y.z += vv.z * s; y.w += vv.w * s;
        }
        out4[f] = y;
    }
}

extern "C" void kernel_launch(void* const* d_in, const int* in_sizes, int n_in,
                              void* d_out, int out_size, void* d_ws, size_t ws_size,
                              hipStream_t stream) {
    const float* u = (const float*)d_in[0];
    const float* A = (const float*)d_in[1];
    const float* B = (const float*)d_in[2];
    float* out = (float*)d_out;
    k_arx<<<NB, 256, 0, stream>>>(u, A, B, out);
}

// Round 8
// 20.681 us; speedup vs baseline: 3.4773x; 1.0309x over previous
//
#include <hip/hip_runtime.h>

#define ORD 16
#define LCH 64
#define PCH 16384          // chunks; PCH*LCH = 2^20
#define NB  256            // blocks; CPB own chunks each
#define CPB 64
#define QT  16             // warm-up chunks (0.6561^16*8 ~ 0.009 trunc err)
#define WCH (CPB + QT)     // 80 window chunks per block
#define NG  (WCH / 4)      // 20 4-chunk scan groups
#define XSTR 84            // xs row stride: 4*odd -> b128 conflict-light
#define YSTR 68            // y_s row stride: 4*odd

__global__ __launch_bounds__(256) void k_arx(const float* __restrict__ u,
                                             const float* __restrict__ A_w,
                                             const float* __restrict__ B_w,
                                             float* __restrict__ out) {
    __shared__ float xs[WCH][XSTR];      // 26.9 KB  (FIR output)
    __shared__ float y_s[CPB][YSTR];     // 17.4 KB
    __shared__ float sR[16][ORD][17];    // M^r, r=0..15
    __shared__ float sM16[ORD][17], sM32[ORD][17];
    __shared__ float sG1[ORD][17], sG2[ORD][17], sG3[ORD][17], sG4[ORD][17];
    __shared__ float sW[4][ORD];         // w_q = a . M^(16q)
    __shared__ float sV[ORD][LCH];       // V[j][k] = (a.M^k)[j]
    __shared__ float sd[WCH][17];        // window-chunk end states
    __shared__ float sF[NG][17];         // 4-group inhomogeneous terms
    __shared__ float sS[CPB][17];        // own-chunk entry states

    const int tid = threadIdx.x;
    const int cb  = blockIdx.x * CPB;
    const long gstart = ((long)cb - QT) * LCH;

    // ---- FIR straight from global: xs[w][t] = sum_s b[15-s]*u[.+t+s] ----
    // issued first so HBM latency overlaps the table build below
    {
        float bb[ORD];
        #pragma unroll
        for (int i = 0; i < ORD; ++i) bb[i] = B_w[i];
        for (int idx = tid; idx < WCH * 4; idx += 256) {
            const int w = idx >> 2, t0 = (idx & 3) * 16;
            const long gbase = gstart + (long)w * LCH + t0;
            if (gstart + (long)w * LCH >= 0) {        // block 0 warm-up guard
                float uu[32];
                const float* up = u + gbase;
                #pragma unroll
                for (int m = 0; m < 8; ++m)
                    *(float4*)&uu[4 * m] = *(const float4*)(up + 4 * m);
                float xv[16];
                #pragma unroll
                for (int kk = 0; kk < 16; ++kk) {
                    float x = 0.f;
                    #pragma unroll
                    for (int s = 0; s < ORD; ++s) x += bb[15 - s] * uu[kk + s];
                    xv[kk] = x;
                }
                #pragma unroll
                for (int m = 0; m < 4; ++m)
                    *(float4*)&xs[w][t0 + 4 * m] = *(const float4*)&xv[4 * m];
            }
        }
    }

    // ---- tables ----
    const int ti = tid >> 4, tj = tid & 15;
    sR[0][ti][tj] = (ti == tj) ? 1.f : 0.f;
    sR[1][ti][tj] = (ti == 0) ? A_w[tj] : ((tj == ti - 1) ? 1.f : 0.f);
    if (tid < ORD) sW[0][tid] = A_w[tid];
    __syncthreads();
    int have = 1;
    while (have < 15) {                  // M^2..M^15 by doubling
        const int nn = (have < 15 - have) ? have : (15 - have);
        for (int idx = tid; idx < nn * 256; idx += 256) {
            const int m = (idx >> 8) + 1, ii = (idx >> 4) & 15, jj = idx & 15;
            float acc = 0.f;
            #pragma unroll
            for (int l = 0; l < ORD; ++l) acc += sR[have][ii][l] * sR[m][l][jj];
            sR[have + m][ii][jj] = acc;
        }
        __syncthreads();
        have += nn;
    }
    {   float acc = 0.f;                 // M^16
        #pragma unroll
        for (int l = 0; l < ORD; ++l) acc += sR[15][ti][l] * sR[1][l][tj];
        sM16[ti][tj] = acc; }
    __syncthreads();
    {   float acc = 0.f;                 // M^32 ; sW1
        #pragma unroll
        for (int l = 0; l < ORD; ++l) acc += sM16[ti][l] * sM16[l][tj];
        sM32[ti][tj] = acc;
        if (tid < ORD) {
            float w = 0.f;
            #pragma unroll
            for (int l = 0; l < ORD; ++l) w += sW[0][l] * sM16[l][tid];
            sW[1][tid] = w;
        } }
    __syncthreads();
    {   float acc = 0.f;                 // G = M^64 ; sW2
        #pragma unroll
        for (int l = 0; l < ORD; ++l) acc += sM32[ti][l] * sM32[l][tj];
        sG1[ti][tj] = acc;
        if (tid < ORD) {
            float w = 0.f;
            #pragma unroll
            for (int l = 0; l < ORD; ++l) w += sW[1][l] * sM16[l][tid];
            sW[2][tid] = w;
        } }
    __syncthreads();
    {   float acc = 0.f;                 // G^2 ; sW3
        #pragma unroll
        for (int l = 0; l < ORD; ++l) acc += sG1[ti][l] * sG1[l][tj];
        sG2[ti][tj] = acc;
        if (tid < ORD) {
            float w = 0.f;
            #pragma unroll
            for (int l = 0; l < ORD; ++l) w += sW[2][l] * sM16[l][tid];
            sW[3][tid] = w;
        } }
    __syncthreads();
    {   float a3 = 0.f, a4 = 0.f;        // G^3, G^4
        #pragma unroll
        for (int l = 0; l < ORD; ++l) {
            a3 += sG2[ti][l] * sG1[l][tj];
            a4 += sG2[ti][l] * sG2[l][tj];
        }
        sG3[ti][tj] = a3;
        sG4[ti][tj] = a4; }
    for (int idx = tid; idx < ORD * LCH; idx += 256) {   // V[j][k] = w_q . M^r
        const int k = idx >> 4, jj = idx & 15, q = k >> 4, r = k & 15;
        float acc = 0.f;
        #pragma unroll
        for (int l = 0; l < ORD; ++l) acc += sW[q][l] * sR[r][l][jj];
        sV[jj][k] = acc;
    }
    __syncthreads();

    // ---- serial sim (IIR only): lanes 0..79 own window chunk tid ----
    {
        const int gchunk = cb - QT + tid;
        float yr[ORD];
        #pragma unroll
        for (int i = 0; i < ORD; ++i) yr[i] = 0.f;
        if (tid < WCH && gchunk >= 0) {
            float a[ORD], xv[ORD];
            #pragma unroll
            for (int i = 0; i < ORD; ++i) a[i] = A_w[i];
            for (int k0 = 0; k0 < LCH; k0 += ORD) {
                #pragma unroll
                for (int m = 0; m < 4; ++m)
                    *(float4*)&xv[4 * m] = *(const float4*)&xs[tid][k0 + 4 * m];
                #pragma unroll
                for (int kk = 0; kk < ORD; ++kk) {
                    float y = xv[kk];   // a[0]*y[t-1] added LAST -> 1-FMA chain
                    #pragma unroll
                    for (int i = ORD - 1; i >= 1; --i) y += a[i] * yr[(kk - 1 - i) & 15];
                    y += a[0] * yr[(kk - 1) & 15];
                    yr[kk] = y;
                }
                if (tid >= QT) {
                    #pragma unroll
                    for (int m = 0; m < 4; ++m)
                        *(float4*)&y_s[tid - QT][k0 + 4 * m] = *(const float4*)&yr[4 * m];
                }
            }
        }
        if (tid < WCH) {
            #pragma unroll
            for (int i = 0; i < ORD; ++i) sd[tid][i] = yr[15 - i];
        }
    }
    __syncthreads();

    // ---- f-groups: f_g = G3.d[4g] + G2.d[4g+1] + G1.d[4g+2] + d[4g+3] ----
    for (int idx = tid; idx < NG * ORD; idx += 256) {
        const int g = idx >> 4, jj = idx & 15;
        float acc = sd[4 * g + 3][jj];
        #pragma unroll
        for (int i = 0; i < ORD; ++i) {
            acc += sG3[jj][i] * sd[4 * g][i];
            acc += sG2[jj][i] * sd[4 * g + 1][i];
            acc += sG1[jj][i] * sd[4 * g + 2][i];
        }
        sF[g][jj] = acc;
    }
    __syncthreads();

    // ---- blocked scan: S_{c+4} = G4.S_c + f ; 8 iters per wave ----
    {
        const int l = tid & 63, w = tid >> 6;
        const int j = l & 15, q = l >> 4;
        const float g0 = sG4[j][4 * q + 0], g1 = sG4[j][4 * q + 1];
        const float g2 = sG4[j][4 * q + 2], g3 = sG4[j][4 * q + 3];
        float S = 0.f;                   // ~= entry state of window row 16w
        #pragma unroll
        for (int i = 0; i < 8; ++i) {
            if (i >= 4 && l < 16) sS[16 * w + 4 * (i - 4)][j] = S;
            float p = g0 * __shfl(S, 4 * q + 0, 16) + g1 * __shfl(S, 4 * q + 1, 16)
                    + g2 * __shfl(S, 4 * q + 2, 16) + g3 * __shfl(S, 4 * q + 3, 16);
            p += __shfl_xor(p, 16);
            p += __shfl_xor(p, 32);
            S = p + sF[4 * w + i][j];
        }
    }
    // ---- reconstruct S at c%4 != 0 (data-parallel, 3 rounds) ----
    #pragma unroll
    for (int r = 1; r <= 3; ++r) {
        __syncthreads();
        const int g = tid >> 4, jj = tid & 15;
        float acc = sd[16 + 4 * g + r - 1][jj];
        #pragma unroll
        for (int i = 0; i < ORD; ++i) acc += sG1[jj][i] * sS[4 * g + r - 1][i];
        sS[4 * g + r][jj] = acc;
    }
    __syncthreads();

    // ---- correction + store: out = y_loc + V_k . S_c (b128 / dwordx4) ----
    float4* out4 = (float4*)(out + (long)cb * LCH);
    #pragma unroll
    for (int it = 0; it < 4; ++it) {
        const int f = it * 256 + tid;
        const int row = f >> 4, k4 = f & 15;
        float4 y = *(const float4*)&y_s[row][4 * k4];
        #pragma unroll
        for (int jj = 0; jj < ORD; ++jj) {
            const float s = sS[row][jj];
            const float4 vv = *(const float4*)&sV[jj][4 * k4];
            y.x += vv.x * s; y.y += vv.y * s; y.z += vv.z * s; y.w += vv.w * s;
        }
        out4[f] = y;
    }
}

extern "C" void kernel_launch(void* const* d_in, const int* in_sizes, int n_in,
                              void* d_out, int out_size, void* d_ws, size_t ws_size,
                              hipStream_t stream) {
    const float* u = (const float*)d_in[0];
    const float* A = (const float*)d_in[1];
    const float* B = (const float*)d_in[2];
    float* out = (float*)d_out;
    k_arx<<<NB, 256, 0, stream>>>(u, A, B, out);
}